// Round 12
// baseline (2284.890 us; speedup 1.0000x reference)
//
#include <hip/hip_runtime.h>

// Problem constants (from reference)
#define N_NODES 16384
#define D_EMB   128
#define LIST_CAP 1024           // max common neighbors (max degree ~200 incl. i==j)
#define BM_U64   256            // u64 words per compressed row (2 KB)
#define FLAG_OFF N_NODES        // int idx: layout flag (after status array)
#define BM_OFF_BYTES (1 << 18)  // bitmaps start at 256 KiB into ws
#define WS_NEEDED (BM_OFF_BYTES + (size_t)N_NODES * (BM_U64 * 8)) // ~34 MB

// ---------------------------------------------------------------------------
// Pass 1 (init): blocks 0..63 zero the status array (0=unclaimed, 1=busy,
// 2=done); block 64 probes adjacency encoding. int32-bool: first 16384 u32
// all in {0,1}; byte-bool: some word >1 w.p. ~1.
__global__ __launch_bounds__(256) void init_kernel(
    const unsigned int* __restrict__ words, int* __restrict__ flags)
{
    if (blockIdx.x < 64) {
        flags[blockIdx.x * 256 + threadIdx.x] = 0;
    } else {
        __shared__ int s_any;
        if (threadIdx.x == 0) s_any = 0;
        __syncthreads();
        int any = 0;
        for (int k = threadIdx.x; k < 16384; k += 256)
            if (words[k] > 1u) any = 1;
        if (any) atomicOr(&s_any, 1);
        __syncthreads();
        if (threadIdx.x == 0) flags[FLAG_OFF] = s_any;  // 1 => byte layout
    }
}

// ---------------------------------------------------------------------------
// Pass 2 (fused claim + compress + link): one block per link.
//  - product half written immediately (overlaps everything)
//  - CAS-claim each endpoint row; winner compresses it (streaming pack),
//    per-thread threadfence, barrier, release-store status=2
//  - spin (s_sleep) on status==2 with acquire loads; then u64-AND bitmaps,
//    decode CN indices, gather embeddings, write cn_sum half.
// Claim-by-first-arrival: a spinner only waits on an already-executing
// block, so no deadlock and no dispatch-order assumption.
// int32 PERMUTED layout: u64[t] bit b <-> node ((b>>2)<<10)+(t<<2)+(b&3).
// byte  LINEAR   layout: u64[t] bit b <-> node (t<<6)+b.
__global__ __launch_bounds__(256) void fused_kernel(
    const int* __restrict__ links, const void* __restrict__ adjv,
    const float* __restrict__ emb, float* __restrict__ out,
    int* __restrict__ flags, unsigned long long* __restrict__ bm64,
    int n_links)
{
    const int link = blockIdx.x;
    if (link >= n_links) return;
    const int i = links[2 * link];
    const int j = links[2 * link + 1];
    const int t = threadIdx.x;
    const int byte_layout = flags[FLAG_OFF];
    const size_t obase = (size_t)link * (2 * D_EMB);

    // ---- product half first: these stores fly under the compress stream.
    if (t < D_EMB)
        out[obase + t] = emb[(size_t)i * D_EMB + t] * emb[(size_t)j * D_EMB + t];

    // ---- claim endpoint rows (non-blocking; no hold-and-wait).
    __shared__ int s_own[2];
    if (t == 0) s_own[0] = (atomicCAS(&flags[i], 0, 1) == 0);
    if (t == 1) s_own[1] = (j != i) && (atomicCAS(&flags[j], 0, 1) == 0);
    __syncthreads();
    const int own0 = s_own[0], own1 = s_own[1];

    // ---- compress owned rows (proven streaming pack; dual-stream if both).
    if (!byte_layout) {
        if (own0 | own1) {
            const int rA = own0 ? i : j;
            const uint4* rowA = reinterpret_cast<const uint4*>(
                (const int*)adjv + (size_t)rA * N_NODES);
            if (own0 && own1) {
                const uint4* rowB = reinterpret_cast<const uint4*>(
                    (const int*)adjv + (size_t)j * N_NODES);
                unsigned int lo0 = 0u, hi0 = 0u, lo1 = 0u, hi1 = 0u;
#pragma unroll
                for (int k = 0; k < 8; ++k) {
                    const uint4 a = rowA[k * 256 + t];
                    const uint4 b = rowB[k * 256 + t];
                    lo0 |= (min(a.x,1u) | (min(a.y,1u)<<1) | (min(a.z,1u)<<2) | (min(a.w,1u)<<3)) << (4*k);
                    lo1 |= (min(b.x,1u) | (min(b.y,1u)<<1) | (min(b.z,1u)<<2) | (min(b.w,1u)<<3)) << (4*k);
                }
#pragma unroll
                for (int k = 8; k < 16; ++k) {
                    const uint4 a = rowA[k * 256 + t];
                    const uint4 b = rowB[k * 256 + t];
                    hi0 |= (min(a.x,1u) | (min(a.y,1u)<<1) | (min(a.z,1u)<<2) | (min(a.w,1u)<<3)) << (4*(k-8));
                    hi1 |= (min(b.x,1u) | (min(b.y,1u)<<1) | (min(b.z,1u)<<2) | (min(b.w,1u)<<3)) << (4*(k-8));
                }
                bm64[(size_t)i * BM_U64 + t] = ((unsigned long long)hi0 << 32) | lo0;
                bm64[(size_t)j * BM_U64 + t] = ((unsigned long long)hi1 << 32) | lo1;
            } else {
                unsigned int lo0 = 0u, hi0 = 0u;
#pragma unroll
                for (int k = 0; k < 8; ++k) {
                    const uint4 a = rowA[k * 256 + t];
                    lo0 |= (min(a.x,1u) | (min(a.y,1u)<<1) | (min(a.z,1u)<<2) | (min(a.w,1u)<<3)) << (4*k);
                }
#pragma unroll
                for (int k = 8; k < 16; ++k) {
                    const uint4 a = rowA[k * 256 + t];
                    hi0 |= (min(a.x,1u) | (min(a.y,1u)<<1) | (min(a.z,1u)<<2) | (min(a.w,1u)<<3)) << (4*(k-8));
                }
                bm64[(size_t)rA * BM_U64 + t] = ((unsigned long long)hi0 << 32) | lo0;
            }
        }
    } else {
        for (int s = 0; s < 2; ++s) {
            const int ownS = (s == 0) ? own0 : own1;
            if (!ownS) continue;
            const int r = (s == 0) ? i : j;
            const uint4* row = reinterpret_cast<const uint4*>(
                (const unsigned char*)adjv + (size_t)r * N_NODES);
            unsigned long long bits = 0ull;
#pragma unroll
            for (int q = 0; q < 4; ++q) {
                const uint4 v = row[t * 4 + q];
                const unsigned int arr[4] = {v.x, v.y, v.z, v.w};
#pragma unroll
                for (int a = 0; a < 4; ++a)
#pragma unroll
                    for (int bb = 0; bb < 4; ++bb)
                        if ((arr[a] >> (8 * bb)) & 0xFFu)
                            bits |= 1ull << (q * 16 + a * 4 + bb);
            }
            bm64[(size_t)r * BM_U64 + t] = bits;
        }
    }

    // ---- publish owned rows: every thread fences its own stores, barrier
    // orders all of them before the release-store of status=2.
    if (own0 | own1) {
        __threadfence();
        __syncthreads();
        if (t == 0 && own0)
            __hip_atomic_store(&flags[i], 2, __ATOMIC_RELEASE, __HIP_MEMORY_SCOPE_AGENT);
        if (t == 1 && own1)
            __hip_atomic_store(&flags[j], 2, __ATOMIC_RELEASE, __HIP_MEMORY_SCOPE_AGENT);
    }

    // ---- wait for both rows (skip what we own — already 2).
    if (t == 0)
        while (__hip_atomic_load(&flags[i], __ATOMIC_ACQUIRE, __HIP_MEMORY_SCOPE_AGENT) != 2)
            __builtin_amdgcn_s_sleep(8);
    if (t == 1 && j != i)
        while (__hip_atomic_load(&flags[j], __ATOMIC_ACQUIRE, __HIP_MEMORY_SCOPE_AGENT) != 2)
            __builtin_amdgcn_s_sleep(8);
    __syncthreads();
    // per-thread acquire so every lane's subsequent bm64 loads are ordered
    (void)__hip_atomic_load(&flags[i], __ATOMIC_ACQUIRE, __HIP_MEMORY_SCOPE_AGENT);
    if (j != i)
        (void)__hip_atomic_load(&flags[j], __ATOMIC_ACQUIRE, __HIP_MEMORY_SCOPE_AGENT);

    // ---- AND bitmaps, decode CN indices.
    __shared__ int s_list[LIST_CAP];
    __shared__ int s_count;
    if (t == 0) s_count = 0;
    __syncthreads();

    unsigned long long m = bm64[(size_t)i * BM_U64 + t]
                         & bm64[(size_t)j * BM_U64 + t];
    while (m) {
        const int b = __ffsll(m) - 1;
        m &= m - 1;
        const int node = byte_layout
            ? ((t << 6) + b)
            : (((b >> 2) << 10) + (t << 2) + (b & 3));
        const int pos = atomicAdd(&s_count, 1);
        if (pos < LIST_CAP) s_list[pos] = node;
    }
    __syncthreads();

    int count = s_count;
    if (count > LIST_CAP) count = LIST_CAP;

    // ---- cn_sum half (product already written).
    if (t >= D_EMB) {
        const int d = t - D_EMB;
        float s = 0.0f;
        for (int c = 0; c < count; ++c)
            s += emb[(size_t)s_list[c] * D_EMB + d];
        out[obase + D_EMB + d] = s;
    }
}

// ---------------------------------------------------------------------------
// Fallback (ws too small): direct kernel — reads both full rows per link.
__global__ __launch_bounds__(256) void detect_layout_kernel(
    const unsigned int* __restrict__ words, int* __restrict__ flag)
{
    __shared__ int s_any;
    if (threadIdx.x == 0) s_any = 0;
    __syncthreads();
    int any = 0;
    for (int k = threadIdx.x; k < 16384; k += 256)
        if (words[k] > 1u) any = 1;
    if (any) atomicOr(&s_any, 1);
    __syncthreads();
    if (threadIdx.x == 0) *flag = s_any;
}

__global__ __launch_bounds__(256) void ncn_direct(
    const int* __restrict__ links, const void* __restrict__ adjv,
    const float* __restrict__ emb, float* __restrict__ out,
    const int* __restrict__ flag, int n_links)
{
    const int link = blockIdx.x;
    if (link >= n_links) return;
    const int i = links[2 * link];
    const int j = links[2 * link + 1];

    __shared__ int s_list[LIST_CAP];
    __shared__ int s_count;
    if (threadIdx.x == 0) s_count = 0;
    __syncthreads();

    const int byte_layout = flag ? flag[0] : 0;
    if (byte_layout) {
        const uint4* rowi = reinterpret_cast<const uint4*>(
            (const unsigned char*)adjv + (size_t)i * N_NODES);
        const uint4* rowj = reinterpret_cast<const uint4*>(
            (const unsigned char*)adjv + (size_t)j * N_NODES);
#pragma unroll
        for (int c = 0; c < 4; ++c) {
            const int idx = c * 256 + threadIdx.x;
            const uint4 a = rowi[idx];
            const uint4 bq = rowj[idx];
            unsigned int m[4] = {a.x & bq.x, a.y & bq.y, a.z & bq.z, a.w & bq.w};
            if (m[0] | m[1] | m[2] | m[3]) {
                const int base = idx * 16;
#pragma unroll
                for (int w = 0; w < 4; ++w) {
                    unsigned int v = m[w];
                    if (!v) continue;
#pragma unroll
                    for (int b8 = 0; b8 < 4; ++b8) {
                        if ((v >> (8 * b8)) & 0xFFu) {
                            int pos = atomicAdd(&s_count, 1);
                            if (pos < LIST_CAP) s_list[pos] = base + w * 4 + b8;
                        }
                    }
                }
            }
        }
    } else {
        const uint4* rowi = reinterpret_cast<const uint4*>(
            (const int*)adjv + (size_t)i * N_NODES);
        const uint4* rowj = reinterpret_cast<const uint4*>(
            (const int*)adjv + (size_t)j * N_NODES);
#pragma unroll
        for (int c = 0; c < 16; ++c) {
            const int idx = c * 256 + threadIdx.x;
            const uint4 a = rowi[idx];
            const uint4 bq = rowj[idx];
            const int base = idx * 4;
            if (a.x & bq.x) { int p = atomicAdd(&s_count, 1); if (p < LIST_CAP) s_list[p] = base + 0; }
            if (a.y & bq.y) { int p = atomicAdd(&s_count, 1); if (p < LIST_CAP) s_list[p] = base + 1; }
            if (a.z & bq.z) { int p = atomicAdd(&s_count, 1); if (p < LIST_CAP) s_list[p] = base + 2; }
            if (a.w & bq.w) { int p = atomicAdd(&s_count, 1); if (p < LIST_CAP) s_list[p] = base + 3; }
        }
    }
    __syncthreads();

    int count = s_count;
    if (count > LIST_CAP) count = LIST_CAP;

    const int t = threadIdx.x;
    const size_t obase = (size_t)link * (2 * D_EMB);
    if (t < D_EMB) {
        out[obase + t] = emb[(size_t)i * D_EMB + t] * emb[(size_t)j * D_EMB + t];
    } else {
        const int d = t - D_EMB;
        float s = 0.0f;
        for (int c = 0; c < count; ++c)
            s += emb[(size_t)s_list[c] * D_EMB + d];
        out[obase + D_EMB + d] = s;
    }
}

extern "C" void kernel_launch(void* const* d_in, const int* in_sizes, int n_in,
                              void* d_out, int out_size, void* d_ws, size_t ws_size,
                              hipStream_t stream) {
    const int* links = (const int*)d_in[0];     // int32 [n_links][2]
    const void* adj = d_in[1];                  // bool matrix (encoding probed)
    const float* emb = (const float*)d_in[2];   // fp32 [N_NODES][D_EMB]
    float* out = (float*)d_out;

    const int n_links = in_sizes[0] / 2;

    if (ws_size >= WS_NEEDED) {
        int* flags = (int*)d_ws;
        unsigned long long* bm64 =
            (unsigned long long*)((char*)d_ws + BM_OFF_BYTES);

        init_kernel<<<65, 256, 0, stream>>>((const unsigned int*)adj, flags);
        fused_kernel<<<n_links, 256, 0, stream>>>(
            links, adj, emb, out, flags, bm64, n_links);
    } else {
        int* flag = (ws_size >= sizeof(int)) ? (int*)d_ws : nullptr;
        if (flag) detect_layout_kernel<<<1, 256, 0, stream>>>(
            (const unsigned int*)adj, flag);
        ncn_direct<<<n_links, 256, 0, stream>>>(links, adj, emb, out, flag, n_links);
    }
}

// Round 13
// 180.848 us; speedup vs baseline: 12.6343x; 12.6343x over previous
//
#include <hip/hip_runtime.h>

// Problem constants (from reference)
#define N_NODES 16384
#define D_EMB   128
#define LIST_CAP 1024             // max common neighbors (max degree ~200)
// ws int-array layout
#define HIST_OFF 0                // [16384] histogram over canonical key
#define FLAG_OFF 16384            // [1] layout flag (1 => byte layout)
#define CUM_OFF  16448            // [16384] exclusive prefix (then running offsets)
#define PERM_OFF 32896            // [n_links] sorted link order
#define WS_NEEDED ((PERM_OFF + 16384) * sizeof(int))   // ~193 KB

// ---------------------------------------------------------------------------
// Pass 1: zero histogram; block 64 probes adjacency encoding.
// int32-bool: first 16384 u32 all in {0,1}; byte-bool: some word >1 w.p. ~1.
__global__ __launch_bounds__(256) void zero_probe_kernel(
    const unsigned int* __restrict__ words, int* __restrict__ flags)
{
    if (blockIdx.x < 64) {
        flags[HIST_OFF + blockIdx.x * 256 + threadIdx.x] = 0;
    } else {
        __shared__ int s_any;
        if (threadIdx.x == 0) s_any = 0;
        __syncthreads();
        int any = 0;
        for (int k = threadIdx.x; k < 16384; k += 256)
            if (words[k] > 1u) any = 1;
        if (any) atomicOr(&s_any, 1);
        __syncthreads();
        if (threadIdx.x == 0) flags[FLAG_OFF] = s_any;
    }
}

// Pass 2: histogram links by canonical key min(i,j).
__global__ __launch_bounds__(256) void count_kernel(
    const int* __restrict__ links, int* __restrict__ flags, int n_links)
{
    const int e = blockIdx.x * 256 + threadIdx.x;
    if (e >= n_links) return;
    const int a = min(links[2 * e], links[2 * e + 1]);
    atomicAdd(&flags[HIST_OFF + a], 1);
}

// Pass 3: exclusive prefix sum over the 16384-entry histogram (one block).
__global__ __launch_bounds__(256) void scan_kernel(int* __restrict__ flags)
{
    __shared__ int s_part[256];
    const int t = threadIdx.x;
    const int base = t * 64;
    int sum = 0;
    for (int k = 0; k < 64; ++k) sum += flags[HIST_OFF + base + k];
    s_part[t] = sum;
    __syncthreads();
    if (t == 0) {
        int acc = 0;
        for (int k = 0; k < 256; ++k) { int v = s_part[k]; s_part[k] = acc; acc += v; }
    }
    __syncthreads();
    int acc = s_part[t];
    for (int k = 0; k < 64; ++k) {
        const int v = flags[HIST_OFF + base + k];
        flags[CUM_OFF + base + k] = acc;
        acc += v;
    }
}

// Pass 4: scatter links into sorted order (running offsets in CUM).
__global__ __launch_bounds__(256) void scatter_kernel(
    const int* __restrict__ links, int* __restrict__ flags, int n_links)
{
    const int e = blockIdx.x * 256 + threadIdx.x;
    if (e >= n_links) return;
    const int a = min(links[2 * e], links[2 * e + 1]);
    const int pos = atomicAdd(&flags[CUM_OFF + a], 1);
    flags[PERM_OFF + pos] = e;
}

// Pass 5: direct kernel in sorted order + XCD-chunked swizzle.
// Same-row links land on consecutive blocks of the same XCD -> duplicate
// 64KB row reads hit L2/L3 instead of HBM (R2's loop runs at 6.1 TB/s; the
// win here is pure traffic reduction, ~380 MB of duplicate row reads).
__global__ __launch_bounds__(256) void ncn_sorted_kernel(
    const int* __restrict__ links, const void* __restrict__ adjv,
    const float* __restrict__ emb, float* __restrict__ out,
    const int* __restrict__ flags, int n_links)
{
    int b = blockIdx.x;
    if (b >= n_links) return;
    // bijective XCD chunking when divisible (8 XCDs)
    int s = b;
    if ((n_links & 7) == 0) {
        const int chunk = n_links >> 3;
        s = (b & 7) * chunk + (b >> 3);
    }
    const int lid = flags[PERM_OFF + s];
    const int i0 = links[2 * lid], j0 = links[2 * lid + 1];
    const int i = min(i0, j0), j = max(i0, j0);   // output symmetric in (i,j)

    __shared__ int s_list[LIST_CAP];
    __shared__ int s_count;
    if (threadIdx.x == 0) s_count = 0;
    __syncthreads();

    const int byte_layout = flags[FLAG_OFF];
    if (byte_layout) {
        const uint4* rowi = reinterpret_cast<const uint4*>(
            (const unsigned char*)adjv + (size_t)i * N_NODES);
        const uint4* rowj = reinterpret_cast<const uint4*>(
            (const unsigned char*)adjv + (size_t)j * N_NODES);
#pragma unroll
        for (int c = 0; c < 4; ++c) {
            const int idx = c * 256 + threadIdx.x;
            const uint4 a = rowi[idx];
            const uint4 bq = rowj[idx];
            unsigned int m[4] = {a.x & bq.x, a.y & bq.y, a.z & bq.z, a.w & bq.w};
            if (m[0] | m[1] | m[2] | m[3]) {
                const int base = idx * 16;
#pragma unroll
                for (int w = 0; w < 4; ++w) {
                    unsigned int v = m[w];
                    if (!v) continue;
#pragma unroll
                    for (int b8 = 0; b8 < 4; ++b8) {
                        if ((v >> (8 * b8)) & 0xFFu) {
                            int pos = atomicAdd(&s_count, 1);
                            if (pos < LIST_CAP) s_list[pos] = base + w * 4 + b8;
                        }
                    }
                }
            }
        }
    } else {
        const uint4* rowi = reinterpret_cast<const uint4*>(
            (const int*)adjv + (size_t)i * N_NODES);
        const uint4* rowj = reinterpret_cast<const uint4*>(
            (const int*)adjv + (size_t)j * N_NODES);
#pragma unroll
        for (int c = 0; c < 16; ++c) {
            const int idx = c * 256 + threadIdx.x;
            const uint4 a = rowi[idx];
            const uint4 bq = rowj[idx];
            const int base = idx * 4;
            if (a.x & bq.x) { int p = atomicAdd(&s_count, 1); if (p < LIST_CAP) s_list[p] = base + 0; }
            if (a.y & bq.y) { int p = atomicAdd(&s_count, 1); if (p < LIST_CAP) s_list[p] = base + 1; }
            if (a.z & bq.z) { int p = atomicAdd(&s_count, 1); if (p < LIST_CAP) s_list[p] = base + 2; }
            if (a.w & bq.w) { int p = atomicAdd(&s_count, 1); if (p < LIST_CAP) s_list[p] = base + 3; }
        }
    }
    __syncthreads();

    int count = s_count;
    if (count > LIST_CAP) count = LIST_CAP;

    const int t = threadIdx.x;
    const size_t obase = (size_t)lid * (2 * D_EMB);
    if (t < D_EMB) {
        out[obase + t] = emb[(size_t)i * D_EMB + t] * emb[(size_t)j * D_EMB + t];
    } else {
        const int d = t - D_EMB;
        float ssum = 0.0f;
        for (int c = 0; c < count; ++c)
            ssum += emb[(size_t)s_list[c] * D_EMB + d];
        out[obase + D_EMB + d] = ssum;
    }
}

// ---------------------------------------------------------------------------
// Fallback (ws too small): plain direct kernel.
__global__ __launch_bounds__(256) void detect_layout_kernel(
    const unsigned int* __restrict__ words, int* __restrict__ flag)
{
    __shared__ int s_any;
    if (threadIdx.x == 0) s_any = 0;
    __syncthreads();
    int any = 0;
    for (int k = threadIdx.x; k < 16384; k += 256)
        if (words[k] > 1u) any = 1;
    if (any) atomicOr(&s_any, 1);
    __syncthreads();
    if (threadIdx.x == 0) *flag = s_any;
}

__global__ __launch_bounds__(256) void ncn_direct(
    const int* __restrict__ links, const void* __restrict__ adjv,
    const float* __restrict__ emb, float* __restrict__ out,
    const int* __restrict__ flag, int n_links)
{
    const int link = blockIdx.x;
    if (link >= n_links) return;
    const int i = links[2 * link];
    const int j = links[2 * link + 1];

    __shared__ int s_list[LIST_CAP];
    __shared__ int s_count;
    if (threadIdx.x == 0) s_count = 0;
    __syncthreads();

    const int byte_layout = flag ? flag[0] : 0;
    if (byte_layout) {
        const uint4* rowi = reinterpret_cast<const uint4*>(
            (const unsigned char*)adjv + (size_t)i * N_NODES);
        const uint4* rowj = reinterpret_cast<const uint4*>(
            (const unsigned char*)adjv + (size_t)j * N_NODES);
#pragma unroll
        for (int c = 0; c < 4; ++c) {
            const int idx = c * 256 + threadIdx.x;
            const uint4 a = rowi[idx];
            const uint4 bq = rowj[idx];
            unsigned int m[4] = {a.x & bq.x, a.y & bq.y, a.z & bq.z, a.w & bq.w};
            if (m[0] | m[1] | m[2] | m[3]) {
                const int base = idx * 16;
#pragma unroll
                for (int w = 0; w < 4; ++w) {
                    unsigned int v = m[w];
                    if (!v) continue;
#pragma unroll
                    for (int b8 = 0; b8 < 4; ++b8) {
                        if ((v >> (8 * b8)) & 0xFFu) {
                            int pos = atomicAdd(&s_count, 1);
                            if (pos < LIST_CAP) s_list[pos] = base + w * 4 + b8;
                        }
                    }
                }
            }
        }
    } else {
        const uint4* rowi = reinterpret_cast<const uint4*>(
            (const int*)adjv + (size_t)i * N_NODES);
        const uint4* rowj = reinterpret_cast<const uint4*>(
            (const int*)adjv + (size_t)j * N_NODES);
#pragma unroll
        for (int c = 0; c < 16; ++c) {
            const int idx = c * 256 + threadIdx.x;
            const uint4 a = rowi[idx];
            const uint4 bq = rowj[idx];
            const int base = idx * 4;
            if (a.x & bq.x) { int p = atomicAdd(&s_count, 1); if (p < LIST_CAP) s_list[p] = base + 0; }
            if (a.y & bq.y) { int p = atomicAdd(&s_count, 1); if (p < LIST_CAP) s_list[p] = base + 1; }
            if (a.z & bq.z) { int p = atomicAdd(&s_count, 1); if (p < LIST_CAP) s_list[p] = base + 2; }
            if (a.w & bq.w) { int p = atomicAdd(&s_count, 1); if (p < LIST_CAP) s_list[p] = base + 3; }
        }
    }
    __syncthreads();

    int count = s_count;
    if (count > LIST_CAP) count = LIST_CAP;

    const int t = threadIdx.x;
    const size_t obase = (size_t)link * (2 * D_EMB);
    if (t < D_EMB) {
        out[obase + t] = emb[(size_t)i * D_EMB + t] * emb[(size_t)j * D_EMB + t];
    } else {
        const int d = t - D_EMB;
        float s = 0.0f;
        for (int c = 0; c < count; ++c)
            s += emb[(size_t)s_list[c] * D_EMB + d];
        out[obase + D_EMB + d] = s;
    }
}

extern "C" void kernel_launch(void* const* d_in, const int* in_sizes, int n_in,
                              void* d_out, int out_size, void* d_ws, size_t ws_size,
                              hipStream_t stream) {
    const int* links = (const int*)d_in[0];     // int32 [n_links][2]
    const void* adj = d_in[1];                  // bool matrix (encoding probed)
    const float* emb = (const float*)d_in[2];   // fp32 [N_NODES][D_EMB]
    float* out = (float*)d_out;

    const int n_links = in_sizes[0] / 2;

    if (ws_size >= WS_NEEDED && n_links <= 16384) {
        int* flags = (int*)d_ws;
        zero_probe_kernel<<<65, 256, 0, stream>>>(
            (const unsigned int*)adj, flags);
        count_kernel<<<(n_links + 255) / 256, 256, 0, stream>>>(
            links, flags, n_links);
        scan_kernel<<<1, 256, 0, stream>>>(flags);
        scatter_kernel<<<(n_links + 255) / 256, 256, 0, stream>>>(
            links, flags, n_links);
        ncn_sorted_kernel<<<n_links, 256, 0, stream>>>(
            links, adj, emb, out, flags, n_links);
    } else {
        int* flag = (ws_size >= sizeof(int)) ? (int*)d_ws : nullptr;
        if (flag) detect_layout_kernel<<<1, 256, 0, stream>>>(
            (const unsigned int*)adj, flag);
        ncn_direct<<<n_links, 256, 0, stream>>>(links, adj, emb, out, flag, n_links);
    }
}